// Round 3
// baseline (121.188 us; speedup 1.0000x reference)
//
#include <hip/hip_runtime.h>
#include <hip/hip_bf16.h>

// Problem constants (fixed by setup_inputs)
#define FIN 250
#define NROWS 129024              // 2048*63 nodes
#define NSTRIPES (NROWS / 16)     // 8064 stripes of 16 rows
#define TOTXF (NROWS * FIN)       // 32256000 floats in x
#define NBLOCKS 256
#define WAVES_PER_BLOCK 12
#define NWAVES_TOT (NBLOCKS * WAVES_PER_BLOCK)   // 3072

typedef short short8 __attribute__((ext_vector_type(8)));
typedef float f32x4 __attribute__((ext_vector_type(4)));

__device__ __forceinline__ short f2bf(float f) {
    __bf16 b = (__bf16)f;           // RNE convert
    return __builtin_bit_cast(short, b);
}

// Issue the 32 float2 loads for one stripe's A slice (lane layout: row=m, k=kg*8+kk*32+0..7).
// Fast path: single base pointer + immediate offsets (stripe known in-bounds).
__device__ __forceinline__ void load_stripe_fast(float2 (&buf)[32], const float* __restrict__ x,
                                                 int stripe, int m, int kg) {
    const float* base = x + (unsigned)(stripe * 16 + m) * FIN + (unsigned)(kg * 8);
    #pragma unroll
    for (int kk = 0; kk < 8; ++kk) {
        #pragma unroll
        for (int p = 0; p < 4; ++p) {
            buf[kk * 4 + p] = *(const float2*)(base + kk * 32 + p * 2);
        }
    }
}

// Safe path (last stripe only): clamp each index in-bounds; k>=250 overreach hits zeroed W rows.
__device__ __forceinline__ void load_stripe_safe(float2 (&buf)[32], const float* __restrict__ x,
                                                 int stripe, int m, int kg) {
    unsigned fbase = (unsigned)(stripe * 16 + m) * FIN + (unsigned)(kg * 8);
    #pragma unroll
    for (int kk = 0; kk < 8; ++kk) {
        #pragma unroll
        for (int p = 0; p < 4; ++p) {
            unsigned idx = fbase + (unsigned)(kk * 32 + p * 2);
            idx = idx > (TOTXF - 2u) ? (TOTXF - 2u) : idx;
            buf[kk * 4 + p] = *(const float2*)(x + idx);
        }
    }
}

// MFMA + store for one col-half (8 nf frags) of a stripe, using prebuilt A-fragments.
__device__ __forceinline__ void mfma_half(const short8 (&af)[8],
                                          const unsigned short* wt,
                                          float* __restrict__ out,
                                          int stripe, int half, int m, int kg,
                                          unsigned bswz, const float (&bcol)[16]) {
    const f32x4 zero = {0.f, 0.f, 0.f, 0.f};
    f32x4 acc[8];
    #pragma unroll
    for (int nf = 0; nf < 8; ++nf) acc[nf] = zero;

    const unsigned chbase = (unsigned)(half * 128) * 512u;
    #pragma unroll
    for (int kk = 0; kk < 8; ++kk) {
        #pragma unroll
        for (int nf = 0; nf < 8; ++nf) {
            unsigned off = chbase + (unsigned)(nf * 16 + m) * 512u
                         + (((unsigned)(kk * 64 + kg * 16)) ^ bswz);
            short8 bf = *(const short8*)((const char*)wt + off);
            acc[nf] = __builtin_amdgcn_mfma_f32_16x16x32_bf16(af[kk], bf, acc[nf], 0, 0, 0);
        }
    }
    // C/D layout: col=lane&15(=m), row=(lane>>4)*4+j
    unsigned obase = (unsigned)(stripe * 16 + kg * 4) * FIN + (unsigned)(half * 128 + m);
    #pragma unroll
    for (int nf = 0; nf < 8; ++nf) {
        if (half == 0 || nf < 7 || m < 10) {   // mask cols 250..255
            float b = bcol[half * 8 + nf];
            #pragma unroll
            for (int j = 0; j < 4; ++j) {
                out[obase + (unsigned)(j * FIN) + (unsigned)(nf * 16)] = acc[nf][j] + b;
            }
        }
    }
}

__global__ void __launch_bounds__(768, 3)
gat_gemm(const float* __restrict__ x, const float* __restrict__ W,
         const float* __restrict__ bias, float* __restrict__ out)
{
    // W^T bf16, [c(256)][k(256 padded)], 512 B/row, XOR-swizzled. 128 KiB.
    __shared__ __align__(16) unsigned short wt[256 * 256];

    const int tid = threadIdx.x;

    // Zero LDS (covers k>=250 and c>=250 pads)
    {
        uint4* p = (uint4*)wt;
        uint4 z = make_uint4(0u, 0u, 0u, 0u);
        for (int i = tid; i < 8192; i += 768) p[i] = z;
    }
    __syncthreads();

    // Stage W (global [k][c] row-major) -> wt[c][k] bf16, swizzled
    for (int idx = tid; idx < FIN * FIN; idx += 768) {
        unsigned k = (unsigned)idx / FIN;
        unsigned c = (unsigned)idx - k * FIN;
        unsigned off = (c << 9) + ((2u * k) ^ ((c & 7u) << 4));
        *(unsigned short*)((char*)wt + off) = (unsigned short)f2bf(W[idx]);
    }
    __syncthreads();

    const int lane = tid & 63;
    const int m    = lane & 15;
    const int kg   = lane >> 4;
    const unsigned bswz = ((unsigned)(m & 7)) << 4;
    const int gw   = blockIdx.x * WAVES_PER_BLOCK + (tid >> 6);

    float bcol[16];
    #pragma unroll
    for (int nf = 0; nf < 16; ++nf) {
        int c = nf * 16 + m;   // nf<8: half0 cols; nf>=8: half1 cols (128 + (nf-8)*16 + m)
        bcol[nf] = (c < FIN) ? bias[c] : 0.f;
    }

    // Software pipeline: buf(s) in flight across the previous stripe's compute.
    float2 buf[32];
    short8 af[8];

    int s = gw;
    if (s >= NSTRIPES) return;   // (never with 3072 waves)
    if (s < NSTRIPES - 1) load_stripe_fast(buf, x, s, m, kg);
    else                  load_stripe_safe(buf, x, s, m, kg);

    for (;;) {
        // Wait for buf(s), convert to bf16 fragments (buf regs die here)
        #pragma unroll
        for (int kk = 0; kk < 8; ++kk) {
            #pragma unroll
            for (int p = 0; p < 4; ++p) {
                af[kk][2 * p]     = f2bf(buf[kk * 4 + p].x);
                af[kk][2 * p + 1] = f2bf(buf[kk * 4 + p].y);
            }
        }
        // Issue next stripe's loads immediately (hidden under the MFMAs below)
        int snext = s + NWAVES_TOT;
        if (snext < NSTRIPES - 1)      load_stripe_fast(buf, x, snext, m, kg);
        else if (snext == NSTRIPES - 1) load_stripe_safe(buf, x, snext, m, kg);

        mfma_half(af, wt, out, s, 0, m, kg, bswz, bcol);
        mfma_half(af, wt, out, s, 1, m, kg, bswz, bcol);

        if (snext >= NSTRIPES) break;
        s = snext;
    }
}

// Tiny 63-node GAT attention over rows 0..62 of out (holding h+bias).
// Mixing (h+bias) rows is exact: sum(alpha)=1 -> sum a(h+b) = sum a h + b.
__global__ void __launch_bounds__(1024, 1)
gat_attn(const float* __restrict__ att_src, const float* __restrict__ att_dst,
         float* __restrict__ out)
{
    __shared__ float hs[63 * 252];      // h rows 0..62, padded pitch 252
    __shared__ float asrc[64], adst[64];
    __shared__ float alpha[63 * 64];

    const int tid = threadIdx.x;

    for (int idx = tid; idx < 63 * FIN; idx += 1024) {
        int r = idx / FIN, f = idx - r * FIN;
        hs[r * 252 + f] = out[idx];
    }
    __syncthreads();

    // logits: 16 threads per row, shfl-reduce
    {
        int r = tid >> 4, t = tid & 15;
        float s1 = 0.f, s2 = 0.f;
        if (r < 63) {
            for (int k = t; k < FIN; k += 16) {
                float h = hs[r * 252 + k];
                s1 += h * att_src[k];
                s2 += h * att_dst[k];
            }
        }
        #pragma unroll
        for (int o = 8; o >= 1; o >>= 1) {
            s1 += __shfl_xor(s1, o, 16);
            s2 += __shfl_xor(s2, o, 16);
        }
        if (r < 63 && t == 0) { asrc[r] = s1; adst[r] = s2; }
    }
    __syncthreads();

    // softmax per dst row: 16 threads per row
    {
        int d = tid >> 4, t = tid & 15;
        if (d < 63) {
            float ad = adst[d];
            float e_[4];
            float mx = -1e30f;
            #pragma unroll
            for (int q = 0; q < 4; ++q) {
                int sdx = t + q * 16;
                float e = -1e30f;
                if (sdx < 63) {
                    e = asrc[sdx] + ad;
                    e = e > 0.f ? e : 0.2f * e;     // leaky_relu slope 0.2
                }
                e_[q] = e;
                mx = fmaxf(mx, e);
            }
            #pragma unroll
            for (int o = 8; o >= 1; o >>= 1) mx = fmaxf(mx, __shfl_xor(mx, o, 16));
            float den = 0.f;
            #pragma unroll
            for (int q = 0; q < 4; ++q) {
                int sdx = t + q * 16;
                float ex = (sdx < 63) ? __expf(e_[q] - mx) : 0.f;
                e_[q] = ex;
                den += ex;
            }
            #pragma unroll
            for (int o = 8; o >= 1; o >>= 1) den += __shfl_xor(den, o, 16);
            float rd = 1.f / den;
            #pragma unroll
            for (int q = 0; q < 4; ++q) {
                int sdx = t + q * 16;
                if (sdx < 63) alpha[d * 64 + sdx] = e_[q] * rd;
            }
        }
    }
    __syncthreads();

    // mix
    for (int idx = tid; idx < 63 * FIN; idx += 1024) {
        int d = idx / FIN, f = idx - d * FIN;
        float v = 0.f;
        for (int sdx = 0; sdx < 63; ++sdx)
            v += alpha[d * 64 + sdx] * hs[sdx * 252 + f];
        out[idx] = v;
    }
}

extern "C" void kernel_launch(void* const* d_in, const int* in_sizes, int n_in,
                              void* d_out, int out_size, void* d_ws, size_t ws_size,
                              hipStream_t stream) {
    (void)in_sizes; (void)n_in; (void)d_ws; (void)ws_size; (void)out_size;
    const float* x        = (const float*)d_in[0];
    const float* W        = (const float*)d_in[1];
    const float* att_src  = (const float*)d_in[2];
    const float* att_dst  = (const float*)d_in[3];
    const float* bias     = (const float*)d_in[4];
    float* out            = (float*)d_out;

    gat_gemm<<<NBLOCKS, 768, 0, stream>>>(x, W, bias, out);
    gat_attn<<<1, 1024, 0, stream>>>(att_src, att_dst, out);
}